// Round 1
// 392.006 us; speedup vs baseline: 1.0407x; 1.0407x over previous
//
#include <hip/hip_runtime.h>

#define NN 100000   // nodes
#define NE 600000   // edges
#define NG 4096     // graphs
#define FIN 74
#define HD 128
#define NL 3
#define BN_EPS 1e-5f
#define NSCAN 391   // ceil(NN/256)
#define NHISTB 2344 // ceil(NE/256)
#define NTILES 3125 // NN/32
#define NSHADOW 8   // bnsum shadow copies (atomic contention spread)
#define GRID_FUSED 1024

typedef __attribute__((ext_vector_type(8))) short short8;
typedef __attribute__((ext_vector_type(4))) float floatx4;
typedef __attribute__((ext_vector_type(8))) unsigned short bf16x8;  // ushort4/8 collide with HIP headers
typedef __attribute__((ext_vector_type(4))) unsigned short bf16x4;

__device__ __forceinline__ unsigned short f2bf(float f) {
    unsigned u = __float_as_uint(f);
    u += 0x7fff + ((u >> 16) & 1);   // round-to-nearest-even
    return (unsigned short)(u >> 16);
}
__device__ __forceinline__ float bf2f(unsigned short u) {
    return __uint_as_float(((unsigned)u) << 16);
}

// ---------------- fused preprocessing: hist | bounds | wpack ----------------
__global__ __launch_bounds__(256) void k_pre(const int* __restrict__ dst,
                                             int* __restrict__ degi,
                                             const int* __restrict__ batch,
                                             int* __restrict__ gstart,
                                             const float* __restrict__ embW,
                                             const float* __restrict__ convW,
                                             unsigned short* __restrict__ WfE,
                                             unsigned short* __restrict__ WfC) {
    int blk = blockIdx.x;
    int t = threadIdx.x;
    if (blk < NHISTB) {
        int e = blk * 256 + t;
        if (e < NE) atomicAdd(&degi[dst[e]], 1);
    } else if (blk < NHISTB + NSCAN) {
        int n = (blk - NHISTB) * 256 + t;
        if (n >= NN) return;
        int b = batch[n];
        int bp = (n == 0) ? -1 : batch[n - 1];
        for (int g = bp + 1; g <= b; g++) gstart[g] = n;
        if (n == NN - 1)
            for (int g = b + 1; g <= NG; g++) gstart[g] = NN;
    } else {
        int d = (blk - NHISTB - NSCAN) * 256 + t;
        if (d < 12288) {
            int inner = d & 511, outer = d >> 9;
            int kstep = outer % 3, nt = outer / 3;
            int g = inner >> 7, n = (inner >> 3) & 15, j = inner & 7;
            int k = kstep * 32 + g * 8 + j;
            float v = (k < FIN) ? embW[k * HD + nt * 16 + n] : 0.0f;
            WfE[d] = f2bf(v);
        } else {
            int e = d - 12288;
            if (e >= NL * 16384) return;
            int layer = e >> 14, r = e & 16383;
            int j = r & 7, n = (r >> 3) & 15, g = (r >> 7) & 3, kstep = (r >> 9) & 3, nt = r >> 11;
            int k = kstep * 32 + g * 8 + j;
            WfC[e] = f2bf(convW[layer * 16384 + k * HD + nt * 16 + n]);
        }
    }
}

__global__ __launch_bounds__(256) void k_scan1(const int* __restrict__ degi,
                                               int* __restrict__ part) {
    __shared__ int s[256];
    int t = threadIdx.x;
    int idx = blockIdx.x * 256 + t;
    s[t] = (idx < NN) ? degi[idx] : 0;
    __syncthreads();
    for (int off = 128; off > 0; off >>= 1) {
        if (t < off) s[t] += s[t + off];
        __syncthreads();
    }
    if (t == 0) part[blockIdx.x] = s[0];
}

__global__ __launch_bounds__(512) void k_scan2(int* __restrict__ part) {
    __shared__ int s[512];
    int t = threadIdx.x;
    s[t] = (t < NSCAN) ? part[t] : 0;
    __syncthreads();
    for (int off = 1; off < 512; off <<= 1) {
        int v = s[t];
        int a = (t >= off) ? s[t - off] : 0;
        __syncthreads();
        s[t] = v + a;
        __syncthreads();
    }
    if (t < NSCAN) part[t] = (t > 0) ? s[t - 1] : 0;  // exclusive
}

// scan3 + dinv fused
__global__ __launch_bounds__(256) void k_scan3(const int* __restrict__ degi,
                                               const int* __restrict__ part,
                                               int* __restrict__ rowptr,
                                               float* __restrict__ dinv) {
    __shared__ int s[256];
    int t = threadIdx.x;
    int idx = blockIdx.x * 256 + t;
    int v = (idx < NN) ? degi[idx] : 0;
    s[t] = v;
    __syncthreads();
    for (int off = 1; off < 256; off <<= 1) {
        int x = s[t];
        int a = (t >= off) ? s[t - off] : 0;
        __syncthreads();
        s[t] = x + a;
        __syncthreads();
    }
    if (idx < NN) {
        rowptr[idx] = part[blockIdx.x] + (s[t] - v);
        dinv[idx] = rsqrtf((float)v + 1.0f);  // +1 self-loop
    }
    if (idx == 0) rowptr[NN] = NE;
}

__global__ __launch_bounds__(256) void k_fill(const int* __restrict__ src,
                                              const int* __restrict__ dst,
                                              const int* __restrict__ rowptr,
                                              int* __restrict__ cursor,
                                              int* __restrict__ col) {
    int e = blockIdx.x * 256 + threadIdx.x;
    if (e >= NE) return;
    int d = dst[e];
    int pos = rowptr[d] + atomicAdd(&cursor[d], 1);
    col[pos] = src[e];
}

// ---------------- embedding MFMA: A = relu(x @ W + b), bf16 out ----------------
__global__ __launch_bounds__(256) void k_emb(const float* __restrict__ x,
                                             const unsigned short* __restrict__ Wf,
                                             const float* __restrict__ b,
                                             unsigned short* __restrict__ hA) {
    __shared__ __align__(16) unsigned short As[4224];
    int t = threadIdx.x;
    int n0 = blockIdx.x * 32;
    for (int f = t; f < 3072; f += 256) {
        int m = f / 96, kp = f % 96;
        float v = (kp < FIN) ? x[(n0 + m) * FIN + kp] : 0.0f;
        int kstep = kp >> 5, g = (kp >> 3) & 3, j = kp & 7;
        As[(kstep * 4 + g) * 264 + m * 8 + j] = f2bf(v);
    }
    __syncthreads();
    int lane = t & 63, wv = t >> 6;
    int lanelo = lane & 15, g = lane >> 4;
    floatx4 acc[2][2] = {};
#pragma unroll
    for (int kstep = 0; kstep < 3; kstep++) {
        short8 a0 = *(const short8*)&As[(kstep * 4 + g) * 264 + lanelo * 8];
        short8 a1 = *(const short8*)&As[(kstep * 4 + g) * 264 + 128 + lanelo * 8];
        short8 b0 = *(const short8*)&Wf[(((wv * 2 + 0) * 3 + kstep) * 4 + g) * 128 + lanelo * 8];
        short8 b1 = *(const short8*)&Wf[(((wv * 2 + 1) * 3 + kstep) * 4 + g) * 128 + lanelo * 8];
        acc[0][0] = __builtin_amdgcn_mfma_f32_16x16x32_bf16(a0, b0, acc[0][0], 0, 0, 0);
        acc[0][1] = __builtin_amdgcn_mfma_f32_16x16x32_bf16(a0, b1, acc[0][1], 0, 0, 0);
        acc[1][0] = __builtin_amdgcn_mfma_f32_16x16x32_bf16(a1, b0, acc[1][0], 0, 0, 0);
        acc[1][1] = __builtin_amdgcn_mfma_f32_16x16x32_bf16(a1, b1, acc[1][1], 0, 0, 0);
    }
    __syncthreads();  // reuse As as output tile (stride 132)
#pragma unroll
    for (int ns = 0; ns < 2; ns++) {
        int colc = wv * 32 + ns * 16 + lanelo;
        float bias = b[colc];
#pragma unroll
        for (int ms = 0; ms < 2; ms++)
#pragma unroll
            for (int r = 0; r < 4; r++) {
                int rowl = ms * 16 + g * 4 + r;
                As[rowl * 132 + colc] = f2bf(fmaxf(acc[ms][ns][r] + bias, 0.0f));
            }
    }
    __syncthreads();
#pragma unroll
    for (int i = 0; i < 2; i++) {
        int f = t * 8 + i * 2048;
        int m = f >> 7, c = f & 127;
        bf16x4 lo = *(const bf16x4*)&As[m * 132 + c];
        bf16x4 hi = *(const bf16x4*)&As[m * 132 + c + 4];
        bf16x8 o = {lo.x, lo.y, lo.z, lo.w, hi.x, hi.y, hi.z, hi.w};
        *(bf16x8*)&hA[n0 * HD + f] = o;
    }
}

// ---------------- FUSED layer: aggregate-first GCN ----------------
// h_pre_l[n] = ( dinv[n] * ( dinv[n]*act(Ain[n]) + sum_{s in N(n)} dinv[s]*act(Ain[s]) ) ) @ W_l + b_l
// act = identity for layer 0 (emb output already ReLU'd); BN-affine+ReLU for l>=1,
// with BN constants computed inline from the previous layer's shadowed bnsum.
// Also accumulates this layer's BN statistics (sum, sumsq of fp32 h_pre) into
// NSHADOW shadow copies of bnout via register accumulation across a grid-stride
// tile loop + one LDS-reduced atomic drain per block.
template <bool BN>
__global__ __launch_bounds__(256) void k_fused(const unsigned short* __restrict__ Ain,
                                               const int* __restrict__ rowptr,
                                               const int* __restrict__ col,
                                               const float* __restrict__ dinv,
                                               const float* __restrict__ bnprev, // [NSHADOW*256] (BN only)
                                               const float* __restrict__ gamma,
                                               const float* __restrict__ beta,
                                               const unsigned short* __restrict__ Wf,
                                               const float* __restrict__ bias,
                                               float* __restrict__ bnout,        // [NSHADOW*256]
                                               unsigned short* __restrict__ Aout) {
    __shared__ __align__(16) unsigned short As[4224];
    int t = threadIdx.x;
    int sub = t >> 4;        // node slot within half-tile (0..15)
    int lanec = t & 15;      // channel group (8 channels each)
    int k0 = lanec * 8;

    // BN-affine constants for the 8 gather-side channels of this thread
    float sc[8], sh[8];
    if (BN) {
        const float inv_n = 1.0f / (float)NN;
#pragma unroll
        for (int jj = 0; jj < 8; jj++) {
            int c = k0 + jj;
            float s = 0.0f, q = 0.0f;
#pragma unroll
            for (int kk = 0; kk < NSHADOW; kk++) {
                s += bnprev[kk * 256 + c];
                q += bnprev[kk * 256 + 128 + c];
            }
            float mu = s * inv_n;
            float var = q * inv_n - mu * mu;
            float g = gamma[c] * rsqrtf(var + BN_EPS);
            sc[jj] = g;
            sh[jj] = beta[c] - mu * g;
        }
    }

    int lane = t & 63, wv = t >> 6;
    int lanelo = lane & 15, g = lane >> 4;
    float bias0 = bias[wv * 32 + lanelo];
    float bias1 = bias[wv * 32 + 16 + lanelo];
    float ssum[2] = {}, ssq[2] = {};

    for (int tile = blockIdx.x; tile < NTILES; tile += gridDim.x) {
        int n0 = tile * 32;
        // ---- gather phase: 2 passes x 16 nodes, 16 lanes/node ----
#pragma unroll
        for (int p = 0; p < 2; p++) {
            int n = n0 + p * 16 + sub;
            float dn = dinv[n];
            float acc[8];
            bf16x8 u = *(const bf16x8*)&Ain[n * HD + k0];
#pragma unroll
            for (int i = 0; i < 8; i++) {
                float v = bf2f(u[i]);
                if (BN) v = fmaxf(v * sc[i] + sh[i], 0.0f);
                acc[i] = dn * v;   // self-loop: dinv[n]*act_self (outer dinv[n] applied at store)
            }
            int j = rowptr[n], j1 = rowptr[n + 1];
            for (; j + 1 < j1; j += 2) {
                int s0 = col[j], s1 = col[j + 1];
                float d0 = dinv[s0], d1 = dinv[s1];
                bf16x8 v0 = *(const bf16x8*)&Ain[s0 * HD + k0];
                bf16x8 v1 = *(const bf16x8*)&Ain[s1 * HD + k0];
#pragma unroll
                for (int i = 0; i < 8; i++) {
                    float a = bf2f(v0[i]);
                    float b2 = bf2f(v1[i]);
                    if (BN) {
                        a = fmaxf(a * sc[i] + sh[i], 0.0f);
                        b2 = fmaxf(b2 * sc[i] + sh[i], 0.0f);
                    }
                    acc[i] = fmaf(d0, a, acc[i]);
                    acc[i] = fmaf(d1, b2, acc[i]);
                }
            }
            if (j < j1) {
                int s0 = col[j];
                float d0 = dinv[s0];
                bf16x8 v0 = *(const bf16x8*)&Ain[s0 * HD + k0];
#pragma unroll
                for (int i = 0; i < 8; i++) {
                    float a = bf2f(v0[i]);
                    if (BN) a = fmaxf(a * sc[i] + sh[i], 0.0f);
                    acc[i] = fmaf(d0, a, acc[i]);
                }
            }
            // write agg row (scaled by dinv[dst]) into MFMA A-operand layout
            bf16x8 o;
#pragma unroll
            for (int i = 0; i < 8; i++) o[i] = f2bf(acc[i] * dn);
            *(bf16x8*)&As[lanec * 264 + (p * 16 + sub) * 8] = o;
        }
        __syncthreads();
        // ---- MFMA phase (identical to proven k_conv inner loop) ----
        floatx4 macc[2][2] = {};
#pragma unroll
        for (int ks = 0; ks < 4; ks++) {
            short8 a0 = *(const short8*)&As[(ks * 4 + g) * 264 + lanelo * 8];
            short8 a1 = *(const short8*)&As[(ks * 4 + g) * 264 + 128 + lanelo * 8];
            short8 b0 = *(const short8*)&Wf[(((wv * 2 + 0) * 4 + ks) * 4 + g) * 128 + lanelo * 8];
            short8 b1 = *(const short8*)&Wf[(((wv * 2 + 1) * 4 + ks) * 4 + g) * 128 + lanelo * 8];
            macc[0][0] = __builtin_amdgcn_mfma_f32_16x16x32_bf16(a0, b0, macc[0][0], 0, 0, 0);
            macc[0][1] = __builtin_amdgcn_mfma_f32_16x16x32_bf16(a0, b1, macc[0][1], 0, 0, 0);
            macc[1][0] = __builtin_amdgcn_mfma_f32_16x16x32_bf16(a1, b0, macc[1][0], 0, 0, 0);
            macc[1][1] = __builtin_amdgcn_mfma_f32_16x16x32_bf16(a1, b1, macc[1][1], 0, 0, 0);
        }
        __syncthreads();  // reuse As as output tile (stride 132)
        // ---- epilogue: bias + stats + transpose-store ----
#pragma unroll
        for (int ms = 0; ms < 2; ms++)
#pragma unroll
            for (int ns = 0; ns < 2; ns++) {
                int colc = wv * 32 + ns * 16 + lanelo;
                float bb = ns ? bias1 : bias0;
#pragma unroll
                for (int r = 0; r < 4; r++) {
                    int rowl = ms * 16 + g * 4 + r;
                    float v = macc[ms][ns][r] + bb;
                    ssum[ns] += v;
                    ssq[ns] += v * v;
                    As[rowl * 132 + colc] = f2bf(v);
                }
            }
        __syncthreads();
#pragma unroll
        for (int i = 0; i < 2; i++) {
            int f = t * 8 + i * 2048;
            int m = f >> 7, c = f & 127;
            bf16x4 lo = *(const bf16x4*)&As[m * 132 + c];
            bf16x4 hi = *(const bf16x4*)&As[m * 132 + c + 4];
            bf16x8 o = {lo.x, lo.y, lo.z, lo.w, hi.x, hi.y, hi.z, hi.w};
            *(bf16x8*)&Aout[n0 * HD + f] = o;
        }
        __syncthreads();  // As reused by next tile's gather
    }
    // ---- drain stats: LDS reduce then one atomic set per block into shadow ----
    float* ls = (float*)As;
    ls[t] = 0.0f;
    __syncthreads();
    {
        int colc0 = wv * 32 + lanelo;
        atomicAdd(&ls[colc0], ssum[0]);
        atomicAdd(&ls[128 + colc0], ssq[0]);
        atomicAdd(&ls[colc0 + 16], ssum[1]);
        atomicAdd(&ls[128 + colc0 + 16], ssq[1]);
    }
    __syncthreads();
    atomicAdd(&bnout[(blockIdx.x & (NSHADOW - 1)) * 256 + t], ls[t]);
}

// ---------------- pooling: one block per graph; BN affine from shadowed sums ----------------
__global__ __launch_bounds__(128) void k_pool_g(const unsigned short* __restrict__ h,
                                                const float* __restrict__ bnsum,
                                                const float* __restrict__ gamma,
                                                const float* __restrict__ beta,
                                                const int* __restrict__ gstart,
                                                float* __restrict__ gfeat) {
    int g = blockIdx.x;
    int c = threadIdx.x;
    int n0 = gstart[g], n1 = gstart[g + 1];
    const float inv_n = 1.0f / (float)NN;
    float s0 = 0.0f, q0 = 0.0f;
#pragma unroll
    for (int k = 0; k < NSHADOW; k++) {
        s0 += bnsum[k * 256 + c];
        q0 += bnsum[k * 256 + 128 + c];
    }
    float mu = s0 * inv_n;
    float var = q0 * inv_n - mu * mu;
    float sc = gamma[c] * rsqrtf(var + BN_EPS);
    float sh = beta[c] - mu * sc;
    float s = 0.0f, mx = 0.0f;   // post-ReLU >= 0; 0 matches empty-seg guard
    for (int n = n0; n < n1; n++) {
        float v = fmaxf(bf2f(h[n * HD + c]) * sc + sh, 0.0f);
        s += v;
        mx = fmaxf(mx, v);
    }
    float cntf = (float)(n1 - n0);
    gfeat[g * 256 + c] = s / fmaxf(cntf, 1.0f);
    gfeat[g * 256 + HD + c] = mx;
}

// ---------------- MLP head v2: 8 graphs/block, 256 threads, split-K ----------------
__global__ __launch_bounds__(256) void k_mlp(const float* __restrict__ gfeat,
                                             const float* __restrict__ w1,
                                             const float* __restrict__ b1,
                                             const float* __restrict__ w2,
                                             const float* __restrict__ b2,
                                             const float* __restrict__ w3,
                                             const float* __restrict__ b3,
                                             float* __restrict__ out) {
    __shared__ float gs[8][258];
    __shared__ float p1[8][130];
    __shared__ float hs[8][130];
    __shared__ float p2[3][8][66];
    __shared__ float h2s[8][66];
    __shared__ float ps[64];
    int t = threadIdx.x;
    int g0 = blockIdx.x * 8;
    for (int f = t; f < 2048; f += 256) {
        int gi = f >> 8, k = f & 255;
        gs[gi][k] = gfeat[(g0 + gi) * 256 + k];
    }
    __syncthreads();
    {
        int colc = t & 127, half = t >> 7;
        int kb = half * 128;
        float acc[8] = {};
        for (int k = 0; k < 128; k++) {
            float w = w1[(kb + k) * HD + colc];
#pragma unroll
            for (int gi = 0; gi < 8; gi++) acc[gi] += gs[gi][kb + k] * w;
        }
        if (half == 1) {
#pragma unroll
            for (int gi = 0; gi < 8; gi++) p1[gi][colc] = acc[gi];
        }
        __syncthreads();
        if (half == 0) {
            float bias = b1[colc];
#pragma unroll
            for (int gi = 0; gi < 8; gi++)
                hs[gi][colc] = fmaxf(acc[gi] + p1[gi][colc] + bias, 0.0f);
        }
    }
    __syncthreads();
    {
        int colc = t & 63, q = t >> 6;
        int kb = q * 32;
        float acc[8] = {};
        for (int k = 0; k < 32; k++) {
            float w = w2[(kb + k) * 64 + colc];
#pragma unroll
            for (int gi = 0; gi < 8; gi++) acc[gi] += hs[gi][kb + k] * w;
        }
        if (q > 0) {
#pragma unroll
            for (int gi = 0; gi < 8; gi++) p2[q - 1][gi][colc] = acc[gi];
        }
        __syncthreads();
        if (q == 0) {
            float bias = b2[colc];
#pragma unroll
            for (int gi = 0; gi < 8; gi++)
                h2s[gi][colc] = fmaxf(acc[gi] + p2[0][gi][colc] + p2[1][gi][colc]
                                      + p2[2][gi][colc] + bias, 0.0f);
        }
    }
    __syncthreads();
    if (t < 64) {
        int gi = t >> 3, prt = t & 7;
        float p = 0.0f;
#pragma unroll
        for (int k = 0; k < 8; k++) p += h2s[gi][prt * 8 + k] * w3[prt * 8 + k];
        ps[t] = p;
    }
    __syncthreads();
    if (t < 8) {
        float a = b3[0];
#pragma unroll
        for (int i = 0; i < 8; i++) a += ps[t * 8 + i];
        out[g0 + t] = a;
    }
}

extern "C" void kernel_launch(void* const* d_in, const int* in_sizes, int n_in,
                              void* d_out, int out_size, void* d_ws, size_t ws_size,
                              hipStream_t stream) {
    const float* x      = (const float*)d_in[0];
    const int*   eidx   = (const int*)d_in[1];   // [2, NE]: src then dst
    const int*   batch  = (const int*)d_in[2];
    const float* emb_W  = (const float*)d_in[3];
    const float* emb_b  = (const float*)d_in[4];
    const float* conv_W = (const float*)d_in[5];
    const float* conv_b = (const float*)d_in[6];
    const float* gamma  = (const float*)d_in[7];
    const float* beta   = (const float*)d_in[8];
    const float* w1     = (const float*)d_in[9];
    const float* b1     = (const float*)d_in[10];
    const float* w2     = (const float*)d_in[11];
    const float* b2     = (const float*)d_in[12];
    const float* w3     = (const float*)d_in[13];
    const float* b3     = (const float*)d_in[14];
    float* out = (float*)d_out;

    const int* src = eidx;
    const int* dst = eidx + NE;

    // workspace carve-up — bnsum3 / degi / cursor contiguous for ONE zeroing memset
    unsigned short* A = (unsigned short*)d_ws;       // [NN*HD] bf16
    unsigned short* B = A + NN * HD;                 // [NN*HD] bf16
    float* dinv  = (float*)(B + NN * HD);            // [NN]
    float* gfeat = dinv + NN;                        // [NG*256] float
    float* bnsum3= gfeat + NG * 256;                 // [NL*NSHADOW*256] (zeroed)
    int*   degi  = (int*)(bnsum3 + NL * NSHADOW * 256); // [NN]  (zeroed)
    int*   cursor= degi + NN;                        // [NN]      (zeroed)
    int*   gstart= cursor + NN;                      // [NG+1]
    int*   rowptr= gstart + NG + 1;                  // [NN+1]
    int*   part  = rowptr + NN + 1;                  // [NSCAN]
    int*   col   = part + NSCAN;                     // [NE]
    unsigned short* WfE = (unsigned short*)(col + NE);  // [12288]
    unsigned short* WfC = WfE + 12288;                  // [3*16384]

    // ---- single zeroing memset: bnsum3 + degi + cursor ----
    (void)hipMemsetAsync(bnsum3, 0,
                         (NL * NSHADOW * 256) * sizeof(float) + 2 * NN * sizeof(int),
                         stream);
    // fused hist | bounds | wpack
    k_pre<<<NHISTB + NSCAN + 240, 256, 0, stream>>>(dst, degi, batch, gstart,
                                                    emb_W, conv_W, WfE, WfC);
    k_scan1<<<NSCAN, 256, 0, stream>>>(degi, part);
    k_scan2<<<1, 512, 0, stream>>>(part);
    k_scan3<<<NSCAN, 256, 0, stream>>>(degi, part, rowptr, dinv);
    k_fill<<<(NE + 255) / 256, 256, 0, stream>>>(src, dst, rowptr, cursor, col);

    // ---- embedding (bf16 act out) ----
    k_emb<<<NN / 32, 256, 0, stream>>>(x, WfE, emb_b, A);

    // ---- fused layers: gather(act) -> MFMA -> bias+stats, ping-pong A<->B ----
    // l=0: A -> B (no BN on input; emb output already ReLU'd)
    k_fused<false><<<GRID_FUSED, 256, 0, stream>>>(A, rowptr, col, dinv,
                                                   nullptr, nullptr, nullptr,
                                                   WfC, conv_b, bnsum3, B);
    // l=1: B -> A (BN of layer 0 inline)
    k_fused<true><<<GRID_FUSED, 256, 0, stream>>>(B, rowptr, col, dinv,
                                                  bnsum3, gamma, beta,
                                                  WfC + 16384, conv_b + HD,
                                                  bnsum3 + NSHADOW * 256, A);
    // l=2: A -> B (BN of layer 1 inline)
    k_fused<true><<<GRID_FUSED, 256, 0, stream>>>(A, rowptr, col, dinv,
                                                  bnsum3 + NSHADOW * 256,
                                                  gamma + HD, beta + HD,
                                                  WfC + 2 * 16384, conv_b + 2 * HD,
                                                  bnsum3 + 2 * NSHADOW * 256, B);

    // ---- pooling (BN of last layer computed inline, float out) ----
    k_pool_g<<<NG, 128, 0, stream>>>(B, bnsum3 + 2 * NSHADOW * 256,
                                     gamma + 2 * HD, beta + 2 * HD,
                                     gstart, gfeat);

    // ---- MLP head v2 ----
    k_mlp<<<NG / 8, 256, 0, stream>>>(gfeat, w1, b1, w2, b2, w3, b3, out);
}

// Round 2
// 381.448 us; speedup vs baseline: 1.0695x; 1.0277x over previous
//
#include <hip/hip_runtime.h>

#define NN 100000   // nodes
#define NE 600000   // edges
#define NG 4096     // graphs
#define FIN 74
#define HD 128
#define NL 3
#define BN_EPS 1e-5f
#define NSCAN 391   // ceil(NN/256)
#define NHISTB 2344 // ceil(NE/256)
#define NTILES 3125 // NN/32
#define NSHADOW 8   // bnsum shadow copies (atomic contention spread)

typedef __attribute__((ext_vector_type(8))) short short8;
typedef __attribute__((ext_vector_type(4))) float floatx4;
typedef __attribute__((ext_vector_type(8))) unsigned short bf16x8;  // ushort4/8 collide with HIP headers
typedef __attribute__((ext_vector_type(4))) unsigned short bf16x4;

__device__ __forceinline__ unsigned short f2bf(float f) {
    unsigned u = __float_as_uint(f);
    u += 0x7fff + ((u >> 16) & 1);   // round-to-nearest-even
    return (unsigned short)(u >> 16);
}
__device__ __forceinline__ float bf2f(unsigned short u) {
    return __uint_as_float(((unsigned)u) << 16);
}

// ---------------- fused preprocessing: hist | bounds | wpack ----------------
__global__ __launch_bounds__(256) void k_pre(const int* __restrict__ dst,
                                             int* __restrict__ degi,
                                             const int* __restrict__ batch,
                                             int* __restrict__ gstart,
                                             const float* __restrict__ embW,
                                             const float* __restrict__ convW,
                                             unsigned short* __restrict__ WfE,
                                             unsigned short* __restrict__ WfC) {
    int blk = blockIdx.x;
    int t = threadIdx.x;
    if (blk < NHISTB) {
        int e = blk * 256 + t;
        if (e < NE) atomicAdd(&degi[dst[e]], 1);
    } else if (blk < NHISTB + NSCAN) {
        int n = (blk - NHISTB) * 256 + t;
        if (n >= NN) return;
        int b = batch[n];
        int bp = (n == 0) ? -1 : batch[n - 1];
        for (int g = bp + 1; g <= b; g++) gstart[g] = n;
        if (n == NN - 1)
            for (int g = b + 1; g <= NG; g++) gstart[g] = NN;
    } else {
        int d = (blk - NHISTB - NSCAN) * 256 + t;
        if (d < 12288) {
            int inner = d & 511, outer = d >> 9;
            int kstep = outer % 3, nt = outer / 3;
            int g = inner >> 7, n = (inner >> 3) & 15, j = inner & 7;
            int k = kstep * 32 + g * 8 + j;
            float v = (k < FIN) ? embW[k * HD + nt * 16 + n] : 0.0f;
            WfE[d] = f2bf(v);
        } else {
            int e = d - 12288;
            if (e >= NL * 16384) return;
            int layer = e >> 14, r = e & 16383;
            int j = r & 7, n = (r >> 3) & 15, g = (r >> 7) & 3, kstep = (r >> 9) & 3, nt = r >> 11;
            int k = kstep * 32 + g * 8 + j;
            WfC[e] = f2bf(convW[layer * 16384 + k * HD + nt * 16 + n]);
        }
    }
}

__global__ __launch_bounds__(256) void k_scan1(const int* __restrict__ degi,
                                               int* __restrict__ part) {
    __shared__ int s[256];
    int t = threadIdx.x;
    int idx = blockIdx.x * 256 + t;
    s[t] = (idx < NN) ? degi[idx] : 0;
    __syncthreads();
    for (int off = 128; off > 0; off >>= 1) {
        if (t < off) s[t] += s[t + off];
        __syncthreads();
    }
    if (t == 0) part[blockIdx.x] = s[0];
}

__global__ __launch_bounds__(512) void k_scan2(int* __restrict__ part) {
    __shared__ int s[512];
    int t = threadIdx.x;
    s[t] = (t < NSCAN) ? part[t] : 0;
    __syncthreads();
    for (int off = 1; off < 512; off <<= 1) {
        int v = s[t];
        int a = (t >= off) ? s[t - off] : 0;
        __syncthreads();
        s[t] = v + a;
        __syncthreads();
    }
    if (t < NSCAN) part[t] = (t > 0) ? s[t - 1] : 0;  // exclusive
}

// scan3 + dinv fused
__global__ __launch_bounds__(256) void k_scan3(const int* __restrict__ degi,
                                               const int* __restrict__ part,
                                               int* __restrict__ rowptr,
                                               float* __restrict__ dinv) {
    __shared__ int s[256];
    int t = threadIdx.x;
    int idx = blockIdx.x * 256 + t;
    int v = (idx < NN) ? degi[idx] : 0;
    s[t] = v;
    __syncthreads();
    for (int off = 1; off < 256; off <<= 1) {
        int x = s[t];
        int a = (t >= off) ? s[t - off] : 0;
        __syncthreads();
        s[t] = x + a;
        __syncthreads();
    }
    if (idx < NN) {
        rowptr[idx] = part[blockIdx.x] + (s[t] - v);
        dinv[idx] = rsqrtf((float)v + 1.0f);  // +1 self-loop
    }
    if (idx == 0) rowptr[NN] = NE;
}

__global__ __launch_bounds__(256) void k_fill(const int* __restrict__ src,
                                              const int* __restrict__ dst,
                                              const int* __restrict__ rowptr,
                                              int* __restrict__ cursor,
                                              int* __restrict__ col) {
    int e = blockIdx.x * 256 + threadIdx.x;
    if (e >= NE) return;
    int d = dst[e];
    int pos = rowptr[d] + atomicAdd(&cursor[d], 1);
    col[pos] = src[e];
}

// ---------------- embedding MFMA: A = relu(x @ W + b), bf16 out ----------------
__global__ __launch_bounds__(256) void k_emb(const float* __restrict__ x,
                                             const unsigned short* __restrict__ Wf,
                                             const float* __restrict__ b,
                                             unsigned short* __restrict__ hA) {
    __shared__ __align__(16) unsigned short As[4224];
    int t = threadIdx.x;
    int n0 = blockIdx.x * 32;
    for (int f = t; f < 3072; f += 256) {
        int m = f / 96, kp = f % 96;
        float v = (kp < FIN) ? x[(n0 + m) * FIN + kp] : 0.0f;
        int kstep = kp >> 5, g = (kp >> 3) & 3, j = kp & 7;
        As[(kstep * 4 + g) * 264 + m * 8 + j] = f2bf(v);
    }
    __syncthreads();
    int lane = t & 63, wv = t >> 6;
    int lanelo = lane & 15, g = lane >> 4;
    floatx4 acc[2][2] = {};
#pragma unroll
    for (int kstep = 0; kstep < 3; kstep++) {
        short8 a0 = *(const short8*)&As[(kstep * 4 + g) * 264 + lanelo * 8];
        short8 a1 = *(const short8*)&As[(kstep * 4 + g) * 264 + 128 + lanelo * 8];
        short8 b0 = *(const short8*)&Wf[(((wv * 2 + 0) * 3 + kstep) * 4 + g) * 128 + lanelo * 8];
        short8 b1 = *(const short8*)&Wf[(((wv * 2 + 1) * 3 + kstep) * 4 + g) * 128 + lanelo * 8];
        acc[0][0] = __builtin_amdgcn_mfma_f32_16x16x32_bf16(a0, b0, acc[0][0], 0, 0, 0);
        acc[0][1] = __builtin_amdgcn_mfma_f32_16x16x32_bf16(a0, b1, acc[0][1], 0, 0, 0);
        acc[1][0] = __builtin_amdgcn_mfma_f32_16x16x32_bf16(a1, b0, acc[1][0], 0, 0, 0);
        acc[1][1] = __builtin_amdgcn_mfma_f32_16x16x32_bf16(a1, b1, acc[1][1], 0, 0, 0);
    }
    __syncthreads();  // reuse As as output tile (stride 132)
#pragma unroll
    for (int ns = 0; ns < 2; ns++) {
        int colc = wv * 32 + ns * 16 + lanelo;
        float bias = b[colc];
#pragma unroll
        for (int ms = 0; ms < 2; ms++)
#pragma unroll
            for (int r = 0; r < 4; r++) {
                int rowl = ms * 16 + g * 4 + r;
                As[rowl * 132 + colc] = f2bf(fmaxf(acc[ms][ns][r] + bias, 0.0f));
            }
    }
    __syncthreads();
#pragma unroll
    for (int i = 0; i < 2; i++) {
        int f = t * 8 + i * 2048;
        int m = f >> 7, c = f & 127;
        bf16x4 lo = *(const bf16x4*)&As[m * 132 + c];
        bf16x4 hi = *(const bf16x4*)&As[m * 132 + c + 4];
        bf16x8 o = {lo.x, lo.y, lo.z, lo.w, hi.x, hi.y, hi.z, hi.w};
        *(bf16x8*)&hA[n0 * HD + f] = o;
    }
}

// ---------------- FUSED layer: aggregate-first GCN, one 32-node tile per block ----
// h_pre_l[n] = ( dinv[n] * ( dinv[n]*act(Ain[n]) + sum_{s in N(n)} dinv[s]*act(Ain[s]) ) ) @ W_l + b_l
// act = identity for layer 0 (emb output already ReLU'd); BN-affine+ReLU for l>=1.
// BN stats of this layer accumulate in registers, drained once per block into
// NSHADOW shadow copies of bnout.
template <bool BN>
__global__ __launch_bounds__(256) void k_fused(const unsigned short* __restrict__ Ain,
                                               const int* __restrict__ rowptr,
                                               const int* __restrict__ col,
                                               const float* __restrict__ dinv,
                                               const float* __restrict__ bnprev, // [NSHADOW*256] (BN only)
                                               const float* __restrict__ gamma,
                                               const float* __restrict__ beta,
                                               const unsigned short* __restrict__ Wf,
                                               const float* __restrict__ bias,
                                               float* __restrict__ bnout,        // [NSHADOW*256]
                                               unsigned short* __restrict__ Aout) {
    __shared__ __align__(16) unsigned short As[4224];
    int t = threadIdx.x;
    int sub = t >> 4;        // node slot within half-tile (0..15)
    int lanec = t & 15;      // channel group (8 channels each)
    int k0 = lanec * 8;

    // BN-affine constants for the 8 gather-side channels of this thread
    float sc[8], sh[8];
    if (BN) {
        const float inv_n = 1.0f / (float)NN;
#pragma unroll
        for (int jj = 0; jj < 8; jj++) {
            int c = k0 + jj;
            float s = 0.0f, q = 0.0f;
#pragma unroll
            for (int kk = 0; kk < NSHADOW; kk++) {
                s += bnprev[kk * 256 + c];
                q += bnprev[kk * 256 + 128 + c];
            }
            float mu = s * inv_n;
            float var = q * inv_n - mu * mu;
            float g = gamma[c] * rsqrtf(var + BN_EPS);
            sc[jj] = g;
            sh[jj] = beta[c] - mu * g;
        }
    }

    int lane = t & 63, wv = t >> 6;
    int lanelo = lane & 15, g = lane >> 4;
    float bias0 = bias[wv * 32 + lanelo];
    float bias1 = bias[wv * 32 + 16 + lanelo];
    float ssum[2] = {}, ssq[2] = {};

    int n0 = blockIdx.x * 32;
    // ---- gather phase: 2 passes x 16 nodes, 16 lanes/node, 4-wide ILP ----
#pragma unroll
    for (int p = 0; p < 2; p++) {
        int n = n0 + p * 16 + sub;
        float dn = dinv[n];
        float acc[8];
        bf16x8 u = *(const bf16x8*)&Ain[n * HD + k0];
#pragma unroll
        for (int i = 0; i < 8; i++) {
            float v = bf2f(u[i]);
            if (BN) v = fmaxf(v * sc[i] + sh[i], 0.0f);
            acc[i] = dn * v;   // self-loop: dinv[n]*act_self (outer dinv[n] applied at store)
        }
        int j = rowptr[n], j1 = rowptr[n + 1];
        for (; j + 3 < j1; j += 4) {
            int s0 = col[j], s1 = col[j + 1], s2 = col[j + 2], s3 = col[j + 3];
            float d0 = dinv[s0], d1 = dinv[s1], d2 = dinv[s2], d3 = dinv[s3];
            bf16x8 v0 = *(const bf16x8*)&Ain[s0 * HD + k0];
            bf16x8 v1 = *(const bf16x8*)&Ain[s1 * HD + k0];
            bf16x8 v2 = *(const bf16x8*)&Ain[s2 * HD + k0];
            bf16x8 v3 = *(const bf16x8*)&Ain[s3 * HD + k0];
#pragma unroll
            for (int i = 0; i < 8; i++) {
                float a0 = bf2f(v0[i]);
                float a1 = bf2f(v1[i]);
                float a2 = bf2f(v2[i]);
                float a3 = bf2f(v3[i]);
                if (BN) {
                    a0 = fmaxf(a0 * sc[i] + sh[i], 0.0f);
                    a1 = fmaxf(a1 * sc[i] + sh[i], 0.0f);
                    a2 = fmaxf(a2 * sc[i] + sh[i], 0.0f);
                    a3 = fmaxf(a3 * sc[i] + sh[i], 0.0f);
                }
                acc[i] = fmaf(d0, a0, acc[i]);
                acc[i] = fmaf(d1, a1, acc[i]);
                acc[i] = fmaf(d2, a2, acc[i]);
                acc[i] = fmaf(d3, a3, acc[i]);
            }
        }
        for (; j < j1; j++) {
            int s0 = col[j];
            float d0 = dinv[s0];
            bf16x8 v0 = *(const bf16x8*)&Ain[s0 * HD + k0];
#pragma unroll
            for (int i = 0; i < 8; i++) {
                float a = bf2f(v0[i]);
                if (BN) a = fmaxf(a * sc[i] + sh[i], 0.0f);
                acc[i] = fmaf(d0, a, acc[i]);
            }
        }
        // write agg row (scaled by dinv[dst]) into MFMA A-operand layout
        bf16x8 o;
#pragma unroll
        for (int i = 0; i < 8; i++) o[i] = f2bf(acc[i] * dn);
        *(bf16x8*)&As[lanec * 264 + (p * 16 + sub) * 8] = o;
    }
    __syncthreads();
    // ---- MFMA phase (identical to proven k_conv inner loop) ----
    floatx4 macc[2][2] = {};
#pragma unroll
    for (int ks = 0; ks < 4; ks++) {
        short8 a0 = *(const short8*)&As[(ks * 4 + g) * 264 + lanelo * 8];
        short8 a1 = *(const short8*)&As[(ks * 4 + g) * 264 + 128 + lanelo * 8];
        short8 b0 = *(const short8*)&Wf[(((wv * 2 + 0) * 4 + ks) * 4 + g) * 128 + lanelo * 8];
        short8 b1 = *(const short8*)&Wf[(((wv * 2 + 1) * 4 + ks) * 4 + g) * 128 + lanelo * 8];
        macc[0][0] = __builtin_amdgcn_mfma_f32_16x16x32_bf16(a0, b0, macc[0][0], 0, 0, 0);
        macc[0][1] = __builtin_amdgcn_mfma_f32_16x16x32_bf16(a0, b1, macc[0][1], 0, 0, 0);
        macc[1][0] = __builtin_amdgcn_mfma_f32_16x16x32_bf16(a1, b0, macc[1][0], 0, 0, 0);
        macc[1][1] = __builtin_amdgcn_mfma_f32_16x16x32_bf16(a1, b1, macc[1][1], 0, 0, 0);
    }
    __syncthreads();  // reuse As as output tile (stride 132)
    // ---- epilogue: bias + stats + transpose-store ----
#pragma unroll
    for (int ms = 0; ms < 2; ms++)
#pragma unroll
        for (int ns = 0; ns < 2; ns++) {
            int colc = wv * 32 + ns * 16 + lanelo;
            float bb = ns ? bias1 : bias0;
#pragma unroll
            for (int r = 0; r < 4; r++) {
                int rowl = ms * 16 + g * 4 + r;
                float v = macc[ms][ns][r] + bb;
                ssum[ns] += v;
                ssq[ns] += v * v;
                As[rowl * 132 + colc] = f2bf(v);
            }
        }
    __syncthreads();
#pragma unroll
    for (int i = 0; i < 2; i++) {
        int f = t * 8 + i * 2048;
        int m = f >> 7, c = f & 127;
        bf16x4 lo = *(const bf16x4*)&As[m * 132 + c];
        bf16x4 hi = *(const bf16x4*)&As[m * 132 + c + 4];
        bf16x8 o = {lo.x, lo.y, lo.z, lo.w, hi.x, hi.y, hi.z, hi.w};
        *(bf16x8*)&Aout[n0 * HD + f] = o;
    }
    __syncthreads();  // As about to be reused as float scratch
    // ---- drain stats: LDS reduce then one atomic per thread into shadow ----
    float* ls = (float*)As;
    ls[t] = 0.0f;
    __syncthreads();
    {
        int colc0 = wv * 32 + lanelo;
        atomicAdd(&ls[colc0], ssum[0]);
        atomicAdd(&ls[128 + colc0], ssq[0]);
        atomicAdd(&ls[colc0 + 16], ssum[1]);
        atomicAdd(&ls[128 + colc0 + 16], ssq[1]);
    }
    __syncthreads();
    atomicAdd(&bnout[(blockIdx.x & (NSHADOW - 1)) * 256 + t], ls[t]);
}

// ---------------- pooling: one block per graph; BN affine from shadowed sums ----------------
__global__ __launch_bounds__(128) void k_pool_g(const unsigned short* __restrict__ h,
                                                const float* __restrict__ bnsum,
                                                const float* __restrict__ gamma,
                                                const float* __restrict__ beta,
                                                const int* __restrict__ gstart,
                                                float* __restrict__ gfeat) {
    int g = blockIdx.x;
    int c = threadIdx.x;
    int n0 = gstart[g], n1 = gstart[g + 1];
    const float inv_n = 1.0f / (float)NN;
    float s0 = 0.0f, q0 = 0.0f;
#pragma unroll
    for (int k = 0; k < NSHADOW; k++) {
        s0 += bnsum[k * 256 + c];
        q0 += bnsum[k * 256 + 128 + c];
    }
    float mu = s0 * inv_n;
    float var = q0 * inv_n - mu * mu;
    float sc = gamma[c] * rsqrtf(var + BN_EPS);
    float sh = beta[c] - mu * sc;
    float s = 0.0f, mx = 0.0f;   // post-ReLU >= 0; 0 matches empty-seg guard
    for (int n = n0; n < n1; n++) {
        float v = fmaxf(bf2f(h[n * HD + c]) * sc + sh, 0.0f);
        s += v;
        mx = fmaxf(mx, v);
    }
    float cntf = (float)(n1 - n0);
    gfeat[g * 256 + c] = s / fmaxf(cntf, 1.0f);
    gfeat[g * 256 + HD + c] = mx;
}

// ---------------- MLP head v2: 8 graphs/block, 256 threads, split-K ----------------
__global__ __launch_bounds__(256) void k_mlp(const float* __restrict__ gfeat,
                                             const float* __restrict__ w1,
                                             const float* __restrict__ b1,
                                             const float* __restrict__ w2,
                                             const float* __restrict__ b2,
                                             const float* __restrict__ w3,
                                             const float* __restrict__ b3,
                                             float* __restrict__ out) {
    __shared__ float gs[8][258];
    __shared__ float p1[8][130];
    __shared__ float hs[8][130];
    __shared__ float p2[3][8][66];
    __shared__ float h2s[8][66];
    __shared__ float ps[64];
    int t = threadIdx.x;
    int g0 = blockIdx.x * 8;
    for (int f = t; f < 2048; f += 256) {
        int gi = f >> 8, k = f & 255;
        gs[gi][k] = gfeat[(g0 + gi) * 256 + k];
    }
    __syncthreads();
    {
        int colc = t & 127, half = t >> 7;
        int kb = half * 128;
        float acc[8] = {};
        for (int k = 0; k < 128; k++) {
            float w = w1[(kb + k) * HD + colc];
#pragma unroll
            for (int gi = 0; gi < 8; gi++) acc[gi] += gs[gi][kb + k] * w;
        }
        if (half == 1) {
#pragma unroll
            for (int gi = 0; gi < 8; gi++) p1[gi][colc] = acc[gi];
        }
        __syncthreads();
        if (half == 0) {
            float bias = b1[colc];
#pragma unroll
            for (int gi = 0; gi < 8; gi++)
                hs[gi][colc] = fmaxf(acc[gi] + p1[gi][colc] + bias, 0.0f);
        }
    }
    __syncthreads();
    {
        int colc = t & 63, q = t >> 6;
        int kb = q * 32;
        float acc[8] = {};
        for (int k = 0; k < 32; k++) {
            float w = w2[(kb + k) * 64 + colc];
#pragma unroll
            for (int gi = 0; gi < 8; gi++) acc[gi] += hs[gi][kb + k] * w;
        }
        if (q > 0) {
#pragma unroll
            for (int gi = 0; gi < 8; gi++) p2[q - 1][gi][colc] = acc[gi];
        }
        __syncthreads();
        if (q == 0) {
            float bias = b2[colc];
#pragma unroll
            for (int gi = 0; gi < 8; gi++)
                h2s[gi][colc] = fmaxf(acc[gi] + p2[0][gi][colc] + p2[1][gi][colc]
                                      + p2[2][gi][colc] + bias, 0.0f);
        }
    }
    __syncthreads();
    if (t < 64) {
        int gi = t >> 3, prt = t & 7;
        float p = 0.0f;
#pragma unroll
        for (int k = 0; k < 8; k++) p += h2s[gi][prt * 8 + k] * w3[prt * 8 + k];
        ps[t] = p;
    }
    __syncthreads();
    if (t < 8) {
        float a = b3[0];
#pragma unroll
        for (int i = 0; i < 8; i++) a += ps[t * 8 + i];
        out[g0 + t] = a;
    }
}

extern "C" void kernel_launch(void* const* d_in, const int* in_sizes, int n_in,
                              void* d_out, int out_size, void* d_ws, size_t ws_size,
                              hipStream_t stream) {
    const float* x      = (const float*)d_in[0];
    const int*   eidx   = (const int*)d_in[1];   // [2, NE]: src then dst
    const int*   batch  = (const int*)d_in[2];
    const float* emb_W  = (const float*)d_in[3];
    const float* emb_b  = (const float*)d_in[4];
    const float* conv_W = (const float*)d_in[5];
    const float* conv_b = (const float*)d_in[6];
    const float* gamma  = (const float*)d_in[7];
    const float* beta   = (const float*)d_in[8];
    const float* w1     = (const float*)d_in[9];
    const float* b1     = (const float*)d_in[10];
    const float* w2     = (const float*)d_in[11];
    const float* b2     = (const float*)d_in[12];
    const float* w3     = (const float*)d_in[13];
    const float* b3     = (const float*)d_in[14];
    float* out = (float*)d_out;

    const int* src = eidx;
    const int* dst = eidx + NE;

    // workspace carve-up — bnsum3 / degi / cursor contiguous for ONE zeroing memset
    unsigned short* A = (unsigned short*)d_ws;       // [NN*HD] bf16
    unsigned short* B = A + NN * HD;                 // [NN*HD] bf16
    float* dinv  = (float*)(B + NN * HD);            // [NN]
    float* gfeat = dinv + NN;                        // [NG*256] float
    float* bnsum3= gfeat + NG * 256;                 // [NL*NSHADOW*256] (zeroed)
    int*   degi  = (int*)(bnsum3 + NL * NSHADOW * 256); // [NN]  (zeroed)
    int*   cursor= degi + NN;                        // [NN]      (zeroed)
    int*   gstart= cursor + NN;                      // [NG+1]
    int*   rowptr= gstart + NG + 1;                  // [NN+1]
    int*   part  = rowptr + NN + 1;                  // [NSCAN]
    int*   col   = part + NSCAN;                     // [NE]
    unsigned short* WfE = (unsigned short*)(col + NE);  // [12288]
    unsigned short* WfC = WfE + 12288;                  // [3*16384]

    // ---- single zeroing memset: bnsum3 + degi + cursor ----
    (void)hipMemsetAsync(bnsum3, 0,
                         (NL * NSHADOW * 256) * sizeof(float) + 2 * NN * sizeof(int),
                         stream);
    // fused hist | bounds | wpack
    k_pre<<<NHISTB + NSCAN + 240, 256, 0, stream>>>(dst, degi, batch, gstart,
                                                    emb_W, conv_W, WfE, WfC);
    k_scan1<<<NSCAN, 256, 0, stream>>>(degi, part);
    k_scan2<<<1, 512, 0, stream>>>(part);
    k_scan3<<<NSCAN, 256, 0, stream>>>(degi, part, rowptr, dinv);
    k_fill<<<(NE + 255) / 256, 256, 0, stream>>>(src, dst, rowptr, cursor, col);

    // ---- embedding (bf16 act out) ----
    k_emb<<<NN / 32, 256, 0, stream>>>(x, WfE, emb_b, A);

    // ---- fused layers: gather(act) -> MFMA -> bias+stats, ping-pong A<->B ----
    // l=0: A -> B (no BN on input; emb output already ReLU'd)
    k_fused<false><<<NTILES, 256, 0, stream>>>(A, rowptr, col, dinv,
                                               nullptr, nullptr, nullptr,
                                               WfC, conv_b, bnsum3, B);
    // l=1: B -> A (BN of layer 0 inline)
    k_fused<true><<<NTILES, 256, 0, stream>>>(B, rowptr, col, dinv,
                                              bnsum3, gamma, beta,
                                              WfC + 16384, conv_b + HD,
                                              bnsum3 + NSHADOW * 256, A);
    // l=2: A -> B (BN of layer 1 inline)
    k_fused<true><<<NTILES, 256, 0, stream>>>(A, rowptr, col, dinv,
                                              bnsum3 + NSHADOW * 256,
                                              gamma + HD, beta + HD,
                                              WfC + 2 * 16384, conv_b + 2 * HD,
                                              bnsum3 + 2 * NSHADOW * 256, B);

    // ---- pooling (BN of last layer computed inline, float out) ----
    k_pool_g<<<NG, 128, 0, stream>>>(B, bnsum3 + 2 * NSHADOW * 256,
                                     gamma + 2 * HD, beta + 2 * HD,
                                     gstart, gfeat);

    // ---- MLP head v2 ----
    k_mlp<<<NG / 8, 256, 0, stream>>>(gfeat, w1, b1, w2, b2, w3, b3, out);
}

// Round 3
// 355.773 us; speedup vs baseline: 1.1467x; 1.0722x over previous
//
#include <hip/hip_runtime.h>

#define NN 100000   // nodes
#define NE 600000   // edges
#define NG 4096     // graphs
#define FIN 74
#define HD 128
#define NL 3
#define BN_EPS 1e-5f
#define NSCAN 391   // ceil(NN/256)
#define NHISTB 2344 // ceil(NE/256)
#define NTILES 3125 // NN/32
#define NSHADOW 8   // bnsum shadow copies (atomic contention spread)

typedef __attribute__((ext_vector_type(8))) short short8;
typedef __attribute__((ext_vector_type(4))) float floatx4;
typedef __attribute__((ext_vector_type(8))) unsigned short bf16x8;  // ushort4/8 collide with HIP headers
typedef __attribute__((ext_vector_type(4))) unsigned short bf16x4;

__device__ __forceinline__ unsigned short f2bf(float f) {
    unsigned u = __float_as_uint(f);
    u += 0x7fff + ((u >> 16) & 1);   // round-to-nearest-even
    return (unsigned short)(u >> 16);
}
__device__ __forceinline__ float bf2f(unsigned short u) {
    return __uint_as_float(((unsigned)u) << 16);
}

// ---------------- fused preprocessing: hist | bounds | wpack ----------------
__global__ __launch_bounds__(256) void k_pre(const int* __restrict__ dst,
                                             int* __restrict__ degi,
                                             const int* __restrict__ batch,
                                             int* __restrict__ gstart,
                                             const float* __restrict__ embW,
                                             const float* __restrict__ convW,
                                             unsigned short* __restrict__ WfE,
                                             unsigned short* __restrict__ WfC) {
    int blk = blockIdx.x;
    int t = threadIdx.x;
    if (blk < NHISTB) {
        int e = blk * 256 + t;
        if (e < NE) atomicAdd(&degi[dst[e]], 1);
    } else if (blk < NHISTB + NSCAN) {
        int n = (blk - NHISTB) * 256 + t;
        if (n >= NN) return;
        int b = batch[n];
        int bp = (n == 0) ? -1 : batch[n - 1];
        for (int g = bp + 1; g <= b; g++) gstart[g] = n;
        if (n == NN - 1)
            for (int g = b + 1; g <= NG; g++) gstart[g] = NN;
    } else {
        int d = (blk - NHISTB - NSCAN) * 256 + t;
        if (d < 12288) {
            int inner = d & 511, outer = d >> 9;
            int kstep = outer % 3, nt = outer / 3;
            int g = inner >> 7, n = (inner >> 3) & 15, j = inner & 7;
            int k = kstep * 32 + g * 8 + j;
            float v = (k < FIN) ? embW[k * HD + nt * 16 + n] : 0.0f;
            WfE[d] = f2bf(v);
        } else {
            int e = d - 12288;
            if (e >= NL * 16384) return;
            int layer = e >> 14, r = e & 16383;
            int j = r & 7, n = (r >> 3) & 15, g = (r >> 7) & 3, kstep = (r >> 9) & 3, nt = r >> 11;
            int k = kstep * 32 + g * 8 + j;
            WfC[e] = f2bf(convW[layer * 16384 + k * HD + nt * 16 + n]);
        }
    }
}

__global__ __launch_bounds__(256) void k_scan1(const int* __restrict__ degi,
                                               int* __restrict__ part) {
    __shared__ int s[256];
    int t = threadIdx.x;
    int idx = blockIdx.x * 256 + t;
    s[t] = (idx < NN) ? degi[idx] : 0;
    __syncthreads();
    for (int off = 128; off > 0; off >>= 1) {
        if (t < off) s[t] += s[t + off];
        __syncthreads();
    }
    if (t == 0) part[blockIdx.x] = s[0];
}

__global__ __launch_bounds__(512) void k_scan2(int* __restrict__ part) {
    __shared__ int s[512];
    int t = threadIdx.x;
    s[t] = (t < NSCAN) ? part[t] : 0;
    __syncthreads();
    for (int off = 1; off < 512; off <<= 1) {
        int v = s[t];
        int a = (t >= off) ? s[t - off] : 0;
        __syncthreads();
        s[t] = v + a;
        __syncthreads();
    }
    if (t < NSCAN) part[t] = (t > 0) ? s[t - 1] : 0;  // exclusive
}

// scan3 + dinv fused
__global__ __launch_bounds__(256) void k_scan3(const int* __restrict__ degi,
                                               const int* __restrict__ part,
                                               int* __restrict__ rowptr,
                                               float* __restrict__ dinv) {
    __shared__ int s[256];
    int t = threadIdx.x;
    int idx = blockIdx.x * 256 + t;
    int v = (idx < NN) ? degi[idx] : 0;
    s[t] = v;
    __syncthreads();
    for (int off = 1; off < 256; off <<= 1) {
        int x = s[t];
        int a = (t >= off) ? s[t - off] : 0;
        __syncthreads();
        s[t] = x + a;
        __syncthreads();
    }
    if (idx < NN) {
        rowptr[idx] = part[blockIdx.x] + (s[t] - v);
        dinv[idx] = rsqrtf((float)v + 1.0f);  // +1 self-loop
    }
    if (idx == 0) rowptr[NN] = NE;
}

__global__ __launch_bounds__(256) void k_fill(const int* __restrict__ src,
                                              const int* __restrict__ dst,
                                              const int* __restrict__ rowptr,
                                              int* __restrict__ cursor,
                                              int* __restrict__ col) {
    int e = blockIdx.x * 256 + threadIdx.x;
    if (e >= NE) return;
    int d = dst[e];
    int pos = rowptr[d] + atomicAdd(&cursor[d], 1);
    col[pos] = src[e];
}

// ---------------- embedding MFMA: P = dinv * relu(x @ W + b), bf16 out ----------------
__global__ __launch_bounds__(256) void k_emb(const float* __restrict__ x,
                                             const unsigned short* __restrict__ Wf,
                                             const float* __restrict__ b,
                                             const float* __restrict__ dinv,
                                             unsigned short* __restrict__ hA) {
    __shared__ __align__(16) unsigned short As[4224];
    __shared__ float dinvs[32];
    int t = threadIdx.x;
    int n0 = blockIdx.x * 32;
    if (t < 32) dinvs[t] = dinv[n0 + t];
    for (int f = t; f < 3072; f += 256) {
        int m = f / 96, kp = f % 96;
        float v = (kp < FIN) ? x[(n0 + m) * FIN + kp] : 0.0f;
        int kstep = kp >> 5, g = (kp >> 3) & 3, j = kp & 7;
        As[(kstep * 4 + g) * 264 + m * 8 + j] = f2bf(v);
    }
    __syncthreads();
    int lane = t & 63, wv = t >> 6;
    int lanelo = lane & 15, g = lane >> 4;
    floatx4 acc[2][2] = {};
#pragma unroll
    for (int kstep = 0; kstep < 3; kstep++) {
        short8 a0 = *(const short8*)&As[(kstep * 4 + g) * 264 + lanelo * 8];
        short8 a1 = *(const short8*)&As[(kstep * 4 + g) * 264 + 128 + lanelo * 8];
        short8 b0 = *(const short8*)&Wf[(((wv * 2 + 0) * 3 + kstep) * 4 + g) * 128 + lanelo * 8];
        short8 b1 = *(const short8*)&Wf[(((wv * 2 + 1) * 3 + kstep) * 4 + g) * 128 + lanelo * 8];
        acc[0][0] = __builtin_amdgcn_mfma_f32_16x16x32_bf16(a0, b0, acc[0][0], 0, 0, 0);
        acc[0][1] = __builtin_amdgcn_mfma_f32_16x16x32_bf16(a0, b1, acc[0][1], 0, 0, 0);
        acc[1][0] = __builtin_amdgcn_mfma_f32_16x16x32_bf16(a1, b0, acc[1][0], 0, 0, 0);
        acc[1][1] = __builtin_amdgcn_mfma_f32_16x16x32_bf16(a1, b1, acc[1][1], 0, 0, 0);
    }
    __syncthreads();  // reuse As as output tile (stride 132)
#pragma unroll
    for (int ns = 0; ns < 2; ns++) {
        int colc = wv * 32 + ns * 16 + lanelo;
        float bias = b[colc];
#pragma unroll
        for (int ms = 0; ms < 2; ms++)
#pragma unroll
            for (int r = 0; r < 4; r++) {
                int rowl = ms * 16 + g * 4 + r;
                As[rowl * 132 + colc] = f2bf(dinvs[rowl] * fmaxf(acc[ms][ns][r] + bias, 0.0f));
            }
    }
    __syncthreads();
#pragma unroll
    for (int i = 0; i < 2; i++) {
        int f = t * 8 + i * 2048;
        int m = f >> 7, c = f & 127;
        bf16x4 lo = *(const bf16x4*)&As[m * 132 + c];
        bf16x4 hi = *(const bf16x4*)&As[m * 132 + c + 4];
        bf16x8 o = {lo.x, lo.y, lo.z, lo.w, hi.x, hi.y, hi.z, hi.w};
        *(bf16x8*)&hA[n0 * HD + f] = o;
    }
}

// ---------------- BN + ReLU + dinv premultiply: P = dinv * max(sc*hpre+sh, 0) ----
__global__ __launch_bounds__(256) void k_bnact(const unsigned short* __restrict__ hpre,
                                               const float* __restrict__ bnsum,
                                               const float* __restrict__ gamma,
                                               const float* __restrict__ beta,
                                               const float* __restrict__ dinv,
                                               unsigned short* __restrict__ P) {
    int t = threadIdx.x;
    int cg = t & 15, c0 = cg * 8;
    const float inv_n = 1.0f / (float)NN;
    float sc[8], sh[8];
#pragma unroll
    for (int jj = 0; jj < 8; jj++) {
        int c = c0 + jj;
        float s = 0.0f, q = 0.0f;
#pragma unroll
        for (int kk = 0; kk < NSHADOW; kk++) {
            s += bnsum[kk * 256 + c];
            q += bnsum[kk * 256 + 128 + c];
        }
        float mu = s * inv_n;
        float var = q * inv_n - mu * mu;
        float g = gamma[c] * rsqrtf(var + BN_EPS);
        sc[jj] = g;
        sh[jj] = beta[c] - mu * g;
    }
    for (int n = blockIdx.x * 16 + (t >> 4); n < NN; n += gridDim.x * 16) {
        float d = dinv[n];
        bf16x8 u = *(const bf16x8*)&hpre[n * HD + c0];
        bf16x8 o;
#pragma unroll
        for (int i = 0; i < 8; i++)
            o[i] = f2bf(d * fmaxf(bf2f(u[i]) * sc[i] + sh[i], 0.0f));
        *(bf16x8*)&P[n * HD + c0] = o;
    }
}

// ---------------- FUSED layer: pure-sum gather -> MFMA -> bias + stats ----------------
// input P[n] = dinv[n]*act(h[n]) premultiplied; agg[n] = dinv[n]*(P[n] + sum_nbr P[s]);
// h_pre = agg @ W + b; stats (sum, sumsq) drained into NSHADOW shadow copies.
__global__ __launch_bounds__(256, 8) void k_fused(const unsigned short* __restrict__ Ain,
                                                  const int* __restrict__ rowptr,
                                                  const int* __restrict__ col,
                                                  const float* __restrict__ dinv,
                                                  const unsigned short* __restrict__ Wf,
                                                  const float* __restrict__ bias,
                                                  float* __restrict__ bnout,  // [NSHADOW*256]
                                                  unsigned short* __restrict__ Aout) {
    __shared__ __align__(16) unsigned short As[4224];
    int t = threadIdx.x;
    int sub = t >> 4;        // node slot within half-tile (0..15)
    int lanec = t & 15;      // channel group (8 channels each)
    int k0 = lanec * 8;

    int lane = t & 63, wv = t >> 6;
    int lanelo = lane & 15, g = lane >> 4;
    float bias0 = bias[wv * 32 + lanelo];
    float bias1 = bias[wv * 32 + 16 + lanelo];
    float ssum[2] = {}, ssq[2] = {};

    int n0 = blockIdx.x * 32;
    // ---- gather phase: 2 passes x 16 nodes, 16 lanes/node, 4-wide ILP, pure sums ----
#pragma unroll
    for (int p = 0; p < 2; p++) {
        int n = n0 + p * 16 + sub;
        float dn = dinv[n];
        float acc[8];
        bf16x8 u = *(const bf16x8*)&Ain[n * HD + k0];
#pragma unroll
        for (int i = 0; i < 8; i++) acc[i] = bf2f(u[i]);   // self term (premultiplied)
        int j = rowptr[n], j1 = rowptr[n + 1];
        for (; j + 3 < j1; j += 4) {
            int s0 = col[j], s1 = col[j + 1], s2 = col[j + 2], s3 = col[j + 3];
            bf16x8 v0 = *(const bf16x8*)&Ain[s0 * HD + k0];
            bf16x8 v1 = *(const bf16x8*)&Ain[s1 * HD + k0];
            bf16x8 v2 = *(const bf16x8*)&Ain[s2 * HD + k0];
            bf16x8 v3 = *(const bf16x8*)&Ain[s3 * HD + k0];
#pragma unroll
            for (int i = 0; i < 8; i++) {
                float a01 = bf2f(v0[i]) + bf2f(v1[i]);
                float a23 = bf2f(v2[i]) + bf2f(v3[i]);
                acc[i] += a01 + a23;
            }
        }
        for (; j < j1; j++) {
            int s0 = col[j];
            bf16x8 v0 = *(const bf16x8*)&Ain[s0 * HD + k0];
#pragma unroll
            for (int i = 0; i < 8; i++) acc[i] += bf2f(v0[i]);
        }
        // write agg row (scaled by dinv[dst]) into MFMA A-operand layout
        bf16x8 o;
#pragma unroll
        for (int i = 0; i < 8; i++) o[i] = f2bf(acc[i] * dn);
        *(bf16x8*)&As[lanec * 264 + (p * 16 + sub) * 8] = o;
    }
    __syncthreads();
    // ---- MFMA phase (identical to proven k_conv inner loop) ----
    floatx4 macc[2][2] = {};
#pragma unroll
    for (int ks = 0; ks < 4; ks++) {
        short8 a0 = *(const short8*)&As[(ks * 4 + g) * 264 + lanelo * 8];
        short8 a1 = *(const short8*)&As[(ks * 4 + g) * 264 + 128 + lanelo * 8];
        short8 b0 = *(const short8*)&Wf[(((wv * 2 + 0) * 4 + ks) * 4 + g) * 128 + lanelo * 8];
        short8 b1 = *(const short8*)&Wf[(((wv * 2 + 1) * 4 + ks) * 4 + g) * 128 + lanelo * 8];
        macc[0][0] = __builtin_amdgcn_mfma_f32_16x16x32_bf16(a0, b0, macc[0][0], 0, 0, 0);
        macc[0][1] = __builtin_amdgcn_mfma_f32_16x16x32_bf16(a0, b1, macc[0][1], 0, 0, 0);
        macc[1][0] = __builtin_amdgcn_mfma_f32_16x16x32_bf16(a1, b0, macc[1][0], 0, 0, 0);
        macc[1][1] = __builtin_amdgcn_mfma_f32_16x16x32_bf16(a1, b1, macc[1][1], 0, 0, 0);
    }
    __syncthreads();  // reuse As as output tile (stride 132)
    // ---- epilogue: bias + stats + transpose-store ----
#pragma unroll
    for (int ms = 0; ms < 2; ms++)
#pragma unroll
        for (int ns = 0; ns < 2; ns++) {
            int colc = wv * 32 + ns * 16 + lanelo;
            float bb = ns ? bias1 : bias0;
#pragma unroll
            for (int r = 0; r < 4; r++) {
                int rowl = ms * 16 + g * 4 + r;
                float v = macc[ms][ns][r] + bb;
                ssum[ns] += v;
                ssq[ns] += v * v;
                As[rowl * 132 + colc] = f2bf(v);
            }
        }
    __syncthreads();
#pragma unroll
    for (int i = 0; i < 2; i++) {
        int f = t * 8 + i * 2048;
        int m = f >> 7, c = f & 127;
        bf16x4 lo = *(const bf16x4*)&As[m * 132 + c];
        bf16x4 hi = *(const bf16x4*)&As[m * 132 + c + 4];
        bf16x8 o = {lo.x, lo.y, lo.z, lo.w, hi.x, hi.y, hi.z, hi.w};
        *(bf16x8*)&Aout[n0 * HD + f] = o;
    }
    __syncthreads();  // As about to be reused as float scratch
    // ---- drain stats: LDS reduce then one atomic per thread into shadow ----
    float* ls = (float*)As;
    ls[t] = 0.0f;
    __syncthreads();
    {
        int colc0 = wv * 32 + lanelo;
        atomicAdd(&ls[colc0], ssum[0]);
        atomicAdd(&ls[128 + colc0], ssq[0]);
        atomicAdd(&ls[colc0 + 16], ssum[1]);
        atomicAdd(&ls[128 + colc0 + 16], ssq[1]);
    }
    __syncthreads();
    atomicAdd(&bnout[(blockIdx.x & (NSHADOW - 1)) * 256 + t], ls[t]);
}

// ---------------- pooling: one block per graph; BN affine from shadowed sums ----------------
__global__ __launch_bounds__(128) void k_pool_g(const unsigned short* __restrict__ h,
                                                const float* __restrict__ bnsum,
                                                const float* __restrict__ gamma,
                                                const float* __restrict__ beta,
                                                const int* __restrict__ gstart,
                                                float* __restrict__ gfeat) {
    int g = blockIdx.x;
    int c = threadIdx.x;
    int n0 = gstart[g], n1 = gstart[g + 1];
    const float inv_n = 1.0f / (float)NN;
    float s0 = 0.0f, q0 = 0.0f;
#pragma unroll
    for (int k = 0; k < NSHADOW; k++) {
        s0 += bnsum[k * 256 + c];
        q0 += bnsum[k * 256 + 128 + c];
    }
    float mu = s0 * inv_n;
    float var = q0 * inv_n - mu * mu;
    float sc = gamma[c] * rsqrtf(var + BN_EPS);
    float sh = beta[c] - mu * sc;
    float s = 0.0f, mx = 0.0f;   // post-ReLU >= 0; 0 matches empty-seg guard
    for (int n = n0; n < n1; n++) {
        float v = fmaxf(bf2f(h[n * HD + c]) * sc + sh, 0.0f);
        s += v;
        mx = fmaxf(mx, v);
    }
    float cntf = (float)(n1 - n0);
    gfeat[g * 256 + c] = s / fmaxf(cntf, 1.0f);
    gfeat[g * 256 + HD + c] = mx;
}

// ---------------- MLP head v2: 8 graphs/block, 256 threads, split-K ----------------
__global__ __launch_bounds__(256) void k_mlp(const float* __restrict__ gfeat,
                                             const float* __restrict__ w1,
                                             const float* __restrict__ b1,
                                             const float* __restrict__ w2,
                                             const float* __restrict__ b2,
                                             const float* __restrict__ w3,
                                             const float* __restrict__ b3,
                                             float* __restrict__ out) {
    __shared__ float gs[8][258];
    __shared__ float p1[8][130];
    __shared__ float hs[8][130];
    __shared__ float p2[3][8][66];
    __shared__ float h2s[8][66];
    __shared__ float ps[64];
    int t = threadIdx.x;
    int g0 = blockIdx.x * 8;
    for (int f = t; f < 2048; f += 256) {
        int gi = f >> 8, k = f & 255;
        gs[gi][k] = gfeat[(g0 + gi) * 256 + k];
    }
    __syncthreads();
    {
        int colc = t & 127, half = t >> 7;
        int kb = half * 128;
        float acc[8] = {};
        for (int k = 0; k < 128; k++) {
            float w = w1[(kb + k) * HD + colc];
#pragma unroll
            for (int gi = 0; gi < 8; gi++) acc[gi] += gs[gi][kb + k] * w;
        }
        if (half == 1) {
#pragma unroll
            for (int gi = 0; gi < 8; gi++) p1[gi][colc] = acc[gi];
        }
        __syncthreads();
        if (half == 0) {
            float bias = b1[colc];
#pragma unroll
            for (int gi = 0; gi < 8; gi++)
                hs[gi][colc] = fmaxf(acc[gi] + p1[gi][colc] + bias, 0.0f);
        }
    }
    __syncthreads();
    {
        int colc = t & 63, q = t >> 6;
        int kb = q * 32;
        float acc[8] = {};
        for (int k = 0; k < 32; k++) {
            float w = w2[(kb + k) * 64 + colc];
#pragma unroll
            for (int gi = 0; gi < 8; gi++) acc[gi] += hs[gi][kb + k] * w;
        }
        if (q > 0) {
#pragma unroll
            for (int gi = 0; gi < 8; gi++) p2[q - 1][gi][colc] = acc[gi];
        }
        __syncthreads();
        if (q == 0) {
            float bias = b2[colc];
#pragma unroll
            for (int gi = 0; gi < 8; gi++)
                h2s[gi][colc] = fmaxf(acc[gi] + p2[0][gi][colc] + p2[1][gi][colc]
                                      + p2[2][gi][colc] + bias, 0.0f);
        }
    }
    __syncthreads();
    if (t < 64) {
        int gi = t >> 3, prt = t & 7;
        float p = 0.0f;
#pragma unroll
        for (int k = 0; k < 8; k++) p += h2s[gi][prt * 8 + k] * w3[prt * 8 + k];
        ps[t] = p;
    }
    __syncthreads();
    if (t < 8) {
        float a = b3[0];
#pragma unroll
        for (int i = 0; i < 8; i++) a += ps[t * 8 + i];
        out[g0 + t] = a;
    }
}

extern "C" void kernel_launch(void* const* d_in, const int* in_sizes, int n_in,
                              void* d_out, int out_size, void* d_ws, size_t ws_size,
                              hipStream_t stream) {
    const float* x      = (const float*)d_in[0];
    const int*   eidx   = (const int*)d_in[1];   // [2, NE]: src then dst
    const int*   batch  = (const int*)d_in[2];
    const float* emb_W  = (const float*)d_in[3];
    const float* emb_b  = (const float*)d_in[4];
    const float* conv_W = (const float*)d_in[5];
    const float* conv_b = (const float*)d_in[6];
    const float* gamma  = (const float*)d_in[7];
    const float* beta   = (const float*)d_in[8];
    const float* w1     = (const float*)d_in[9];
    const float* b1     = (const float*)d_in[10];
    const float* w2     = (const float*)d_in[11];
    const float* b2     = (const float*)d_in[12];
    const float* w3     = (const float*)d_in[13];
    const float* b3     = (const float*)d_in[14];
    float* out = (float*)d_out;

    const int* src = eidx;
    const int* dst = eidx + NE;

    // workspace carve-up — bnsum3 / degi / cursor contiguous for ONE zeroing memset
    unsigned short* A = (unsigned short*)d_ws;       // [NN*HD] bf16
    unsigned short* B = A + NN * HD;                 // [NN*HD] bf16
    float* dinv  = (float*)(B + NN * HD);            // [NN]
    float* gfeat = dinv + NN;                        // [NG*256] float
    float* bnsum3= gfeat + NG * 256;                 // [NL*NSHADOW*256] (zeroed)
    int*   degi  = (int*)(bnsum3 + NL * NSHADOW * 256); // [NN]  (zeroed)
    int*   cursor= degi + NN;                        // [NN]      (zeroed)
    int*   gstart= cursor + NN;                      // [NG+1]
    int*   rowptr= gstart + NG + 1;                  // [NN+1]
    int*   part  = rowptr + NN + 1;                  // [NSCAN]
    int*   col   = part + NSCAN;                     // [NE]
    unsigned short* WfE = (unsigned short*)(col + NE);  // [12288]
    unsigned short* WfC = WfE + 12288;                  // [3*16384]

    // ---- single zeroing memset: bnsum3 + degi + cursor ----
    (void)hipMemsetAsync(bnsum3, 0,
                         (NL * NSHADOW * 256) * sizeof(float) + 2 * NN * sizeof(int),
                         stream);
    // fused hist | bounds | wpack
    k_pre<<<NHISTB + NSCAN + 240, 256, 0, stream>>>(dst, degi, batch, gstart,
                                                    emb_W, conv_W, WfE, WfC);
    k_scan1<<<NSCAN, 256, 0, stream>>>(degi, part);
    k_scan2<<<1, 512, 0, stream>>>(part);
    k_scan3<<<NSCAN, 256, 0, stream>>>(degi, part, rowptr, dinv);
    k_fill<<<(NE + 255) / 256, 256, 0, stream>>>(src, dst, rowptr, cursor, col);

    // ---- embedding (dinv-premultiplied activated bf16 out) ----
    k_emb<<<NN / 32, 256, 0, stream>>>(x, WfE, emb_b, dinv, A);

    // ---- fused layers: pure-sum gather -> MFMA -> bias+stats ----
    // l=0: A(P0) -> B(h_pre0)
    k_fused<<<NTILES, 256, 0, stream>>>(A, rowptr, col, dinv,
                                        WfC, conv_b, bnsum3, B);
    // BN0 + ReLU + dinv premult: B -> A(P1)
    k_bnact<<<1024, 256, 0, stream>>>(B, bnsum3, gamma, beta, dinv, A);
    // l=1: A(P1) -> B(h_pre1)
    k_fused<<<NTILES, 256, 0, stream>>>(A, rowptr, col, dinv,
                                        WfC + 16384, conv_b + HD,
                                        bnsum3 + NSHADOW * 256, B);
    // BN1 + ReLU + dinv premult: B -> A(P2)
    k_bnact<<<1024, 256, 0, stream>>>(B, bnsum3 + NSHADOW * 256,
                                      gamma + HD, beta + HD, dinv, A);
    // l=2: A(P2) -> B(h_pre2)
    k_fused<<<NTILES, 256, 0, stream>>>(A, rowptr, col, dinv,
                                        WfC + 2 * 16384, conv_b + 2 * HD,
                                        bnsum3 + 2 * NSHADOW * 256, B);

    // ---- pooling (BN of last layer computed inline, float out) ----
    k_pool_g<<<NG, 128, 0, stream>>>(B, bnsum3 + 2 * NSHADOW * 256,
                                     gamma + 2 * HD, beta + 2 * HD,
                                     gstart, gfeat);

    // ---- MLP head v2 ----
    k_mlp<<<NG / 8, 256, 0, stream>>>(gfeat, w1, b1, w2, b2, w3, b3, out);
}